// Round 12
// baseline (651.749 us; speedup 1.0000x reference)
//
#include <hip/hip_runtime.h>
#include <hip/hip_bf16.h>
#include <math.h>

// ---------------------------------------------------------------------------
// sMLP4, time-parallel formulation (exact int8-sliced MFMA, 5 slices):
//   w*2^48 = sum_s d_s 256^s; digits 1..5 used (drop low byte, per-weight
//   err <= 2^-41). Slice dots exact int32; T = Horner(5), I = (double)T*2^-40.
// Round 12: r10 gemm1 structure, but the K-loop barrier is amortized 25x->5x:
//   stage 5 kc x 5 slices (25 KB) per round, double-buffered (51 KB LDS).
//   Per round: stage-write B(g+1), prefetch B(g+2) + ALL 10 A frags(g+1)
//   up front, then 50 barrier-free MFMAs (~1830 cyc) -> the vmcnt(0) drain
//   at each of the 5 barriers finds its loads already complete (r10 paid a
//   ~500-900 cyc LLC-latency drain at every one of 25 barriers).
//   T1 split planes (int32 lo + int16 hi, exact) + XCD nt swizzle kept.
//   Trajectory bit-identical to rounds 9-11.
// ---------------------------------------------------------------------------

#define NSTEPS 50
#define KC1 25                     // real K chunks for layer 1 (800 >= 784)
#define NSL 5                      // digit slices (digits 1..5 of 2^48 fix-pt)

typedef __attribute__((ext_vector_type(4)))  int i32x4;
typedef __attribute__((ext_vector_type(16))) int i32x16;

// fixed workspace layout (bytes, all 256-aligned)
#define OFF_B1     0ull            // i8 [5s][32nt][26kc][1024] = 4,259,840
#define OFF_B2     5111808ull      // i8 [5*4*32*1024]  =   655,360
#define OFF_H1MST  5898240ull      // f64[1024*1024]    = 8,388,608
#define OFF_H1SST  14286848ull     // i8 [1024*1024]    = 1,048,576
#define OFF_H2MST  15335424ull     // f64[1024*128]     = 1,048,576
#define OFF_H2SST  16384000ull     // i8 [1024*128]     =   131,072
#define OFF_ACCST  16515072ull     // f64[1024*10]      =    81,920
#define OFF_AF     16596992ull     // i8 [50*32*26*64*16] = 42,598,400
#define FIXED_END  59195392ull
// per-chunk (C steps): T1L C*4,194,304 ; T1H C*2,097,152 ;
//                      h1sc C*1,048,576 ; T2 C*1,048,576  = 8,388,608/step
#define PERSTEP    8388608ull

#define PREP_BLOCKS 19200          // (4,259,840 + 655,360) / 256

// ---------------------------------------------------------------------------
// threefry2x32, key (0,42), partitionable mode: bits(i) = x0^x1 on ctr (0,i)
// ---------------------------------------------------------------------------
__device__ __forceinline__ unsigned int rotl32(unsigned int v, int d) {
#if __has_builtin(__builtin_amdgcn_alignbit)
  return __builtin_amdgcn_alignbit(v, v, (unsigned int)(32 - d));
#else
  return (v << d) | (v >> (32 - d));
#endif
}

__device__ __forceinline__ unsigned int tf_bits(unsigned int i) {
  const unsigned int ks0 = 0u;
  const unsigned int ks1 = 42u;
  const unsigned int ks2 = 0x1BD11BDAu ^ 0u ^ 42u;
  unsigned int x0 = 0u + ks0;
  unsigned int x1 = i + ks1;
#define TF_RND(r) { x0 += x1; x1 = rotl32(x1, r); x1 ^= x0; }
  TF_RND(13) TF_RND(15) TF_RND(26) TF_RND(6)
  x0 += ks1; x1 += ks2 + 1u;
  TF_RND(17) TF_RND(29) TF_RND(16) TF_RND(24)
  x0 += ks2; x1 += ks0 + 2u;
  TF_RND(13) TF_RND(15) TF_RND(26) TF_RND(6)
  x0 += ks0; x1 += ks1 + 3u;
  TF_RND(17) TF_RND(29) TF_RND(16) TF_RND(24)
  x0 += ks1; x1 += ks2 + 4u;
  TF_RND(13) TF_RND(15) TF_RND(26) TF_RND(6)
  x0 += ks2; x1 += ks0 + 5u;
#undef TF_RND
  return x0 ^ x1;
}

// ---------------------------------------------------------------------------
// spikegen role (one block = 4 waves = 4 (t,mt,kc) groups), steps [t0, ...).
// A-frag: lane holds A[m = mt*32+(lane&31)][k = kc*32+(lane>>5)*16+jj].
// Integer compare: u < x  <=>  (bits>>9) < ceil(x*2^23)   (both exact).
// ---------------------------------------------------------------------------
__device__ __forceinline__ void spike_block(
    const float* __restrict__ x, i32x4* __restrict__ A, int t0, int gblk,
    int tid) {
  int g = gblk * 4 + (tid >> 6);
  int lane = tid & 63;
  int kc = g % 25;
  int r = g / 25;                     // chunk-local tl*32 + mt
  int mt = r & 31;
  int t = t0 + (r >> 5);
  int b = mt * 32 + (lane & 31);
  int j0 = kc * 32 + ((lane >> 5) << 4);
  unsigned int wds[4] = {0u, 0u, 0u, 0u};
  if (j0 < 784) {                     // 784 = 49*16: wave-uniform guard
    unsigned int base = (unsigned int)(t * 1024 + b) * 784u + (unsigned int)j0;
    const float* xp = x + b * 784 + j0;
#pragma unroll
    for (int q = 0; q < 4; ++q) {
      float4 xv = *(const float4*)(xp + 4 * q);
      unsigned int K0 = (unsigned int)(int)ceilf(xv.x * 8388608.0f);
      unsigned int K1 = (unsigned int)(int)ceilf(xv.y * 8388608.0f);
      unsigned int K2 = (unsigned int)(int)ceilf(xv.z * 8388608.0f);
      unsigned int K3 = (unsigned int)(int)ceilf(xv.w * 8388608.0f);
      unsigned int w4 = 0u;
      if ((tf_bits(base + 4 * q + 0) >> 9) < K0) w4 |= 1u;
      if ((tf_bits(base + 4 * q + 1) >> 9) < K1) w4 |= 1u << 8;
      if ((tf_bits(base + 4 * q + 2) >> 9) < K2) w4 |= 1u << 16;
      if ((tf_bits(base + 4 * q + 3) >> 9) < K3) w4 |= 1u << 24;
      wds[q] = w4;
    }
  }
  i32x4 v;
  v.x = (int)wds[0]; v.y = (int)wds[1]; v.z = (int)wds[2]; v.w = (int)wds[3];
  A[(size_t)(((t * 32 + mt) * 26) + kc) * 64 + lane] = v;
}

// ---------------------------------------------------------------------------
// setup: prep (weight slicing) blocks first, chunk-0 spikegen blocks backfill.
// B1 layout (r10, s-major): B1[(((s*32+nt)*26)+kc)*1024 + lane*16 + jj],
// digit s+1 of w*2^48. B2 layout: [(s*4+nt)*32+kc][64][16].
// B-frag (32x32x32 i8): lane holds B[k = kc*32+(lane>>5)*16+jj][n],
// n = nt*32+(lane&31). (HW-validated layout)
// ---------------------------------------------------------------------------
__global__ __launch_bounds__(256) void setup_kernel(
    const float* __restrict__ W1, const float* __restrict__ W2,
    signed char* __restrict__ B1, signed char* __restrict__ B2,
    const float* __restrict__ x, i32x4* __restrict__ A) {
  if (blockIdx.x >= PREP_BLOCKS) {
    spike_block(x, A, 0, blockIdx.x - PREP_BLOCKS, threadIdx.x);
    return;
  }
  int idx = blockIdx.x * 256 + threadIdx.x;
  const int NB1 = NSL * 32 * 26 * 1024;
  const int NB2 = NSL * 4 * 32 * 1024;
  float w;
  int s;
  signed char* dst;
  if (idx < NB1) {
    int jj = idx & 15;
    int lane = (idx >> 4) & 63;
    int kc = (idx >> 10) % 26;
    int rest = (idx >> 10) / 26;
    int nt = rest & 31;
    s = rest >> 5;                    // 0..4
    int k = kc * 32 + ((lane >> 5) << 4) + jj;
    int o = nt * 32 + (lane & 31);
    w = (o < 1000 && k < 784) ? W1[o * 784 + k] : 0.0f;
    dst = B1 + idx;
  } else {
    int m = idx - NB1;
    if (m >= NB2) return;
    int jj = m & 15;
    int lane = (m >> 4) & 63;
    int kc = (m >> 10) & 31;
    int rest = (m >> 10) >> 5;
    int nt = rest & 3;
    s = rest >> 2;                    // 0..4
    int k = kc * 32 + ((lane >> 5) << 4) + jj;
    int o = nt * 32 + (lane & 31);
    w = (o < 100 && k < 1000) ? W2[o * 1000 + k] : 0.0f;
    dst = B2 + m;
  }
  long long V = llrint((double)w * 281474976710656.0);  // w * 2^48, exact
  signed char d = 0;
  for (int q = 0; q <= s + 1; ++q) {  // extract digit s+1
    d = (signed char)(V & 0xFF);
    V = (V - (long long)d) >> 8;
  }
  *dst = d;
}

// ---------------------------------------------------------------------------
// GEMM1: M=C*1024 (t-batched), N=1024, K=800 (25 chunks = 5 rounds x 5 kc),
// 5 slices. Block = 4 waves, one nt. Per ROUND (5 kc): cooperative stage of
// 25 fragments (25 KB) into LDS (double-buffered, 51 KB total), all A frags
// for the NEXT round prefetched up front, then 50 MFMAs per wave with no
// barrier. Only 5 __syncthreads in the K-loop -> the vmcnt drain is paid 5x
// not 25x, and each drain's loads have had a full round (~1800 cyc) to land.
// Each wave: 2 m-tiles x 5 slices (160 AGPR), ~150 VGPR -> 1 wave/SIMD,
// 512-reg budget, no spill. XCD swizzle: nt = (id&7)*4 + ((id>>3)&3).
// T1 out = int32 lo + int16 hi planes (exact).
// ---------------------------------------------------------------------------
__global__ __launch_bounds__(256, 1) void gemm1_kernel(
    const signed char* __restrict__ Bf, const signed char* __restrict__ Afc,
    int* __restrict__ T1L, short* __restrict__ T1H) {
  __shared__ i32x4 bls[2 * 1600];      // 2 rounds x 25 frags x 64 lanes = 51,200 B
  int tid = threadIdx.x, lane = tid & 63, wv = tid >> 6;
  int id = blockIdx.x;
  int low5 = id & 31;
  int nt = ((low5 & 7) << 2) | ((low5 >> 3) & 3);   // XCD-pinned nt
  int mg = id >> 5;
  int tl = mg >> 2;
  int q  = mg & 3;
  int mtA = q * 8 + wv * 2;            // and mtA+1

  const i32x4* ApA = (const i32x4*)Afc + (size_t)((tl * 32 + mtA) * 26) * 64 + lane;
  const i32x4* ApB = ApA + 26 * 64;
  const i32x4* Bp = (const i32x4*)Bf;

  // staging map: element e = tid + 256*j (e < 1600) of one round,
  // frag f = e>>6 = kcr*5+s, lane_e = e&63;
  // global i32x4 index = ((s*32+nt)*26 + g*5+kcr)*64 + lane_e  (+320 per round)
  const i32x4* gsrc[7];
  bool gok[7];
#pragma unroll
  for (int j = 0; j < 7; ++j) {
    int e = tid + 256 * j;
    gok[j] = (e < 1600);
    int ec = gok[j] ? e : 0;
    int f = ec >> 6;
    int s = f % 5;
    int kcr = f / 5;
    int le = ec & 63;
    gsrc[j] = Bp + (size_t)(((s * 32 + nt) * 26) + kcr) * 64 + le;
  }

  i32x16 CA[NSL], CB[NSL];
#pragma unroll
  for (int s = 0; s < NSL; ++s)
#pragma unroll
    for (int i = 0; i < 16; ++i) { CA[s][i] = 0; CB[s][i] = 0; }

  // prologue: load+stage round 0, preload round-1 stage regs, load round-0 A
  i32x4 rb[7];
#pragma unroll
  for (int j = 0; j < 7; ++j) if (gok[j]) rb[j] = gsrc[j][0];
#pragma unroll
  for (int j = 0; j < 7; ++j) if (gok[j]) bls[tid + 256 * j] = rb[j];
#pragma unroll
  for (int j = 0; j < 7; ++j) if (gok[j]) rb[j] = gsrc[j][320];

  i32x4 aA[5], aB[5], nA[5], nB[5];
#pragma unroll
  for (int i = 0; i < 5; ++i) {
    aA[i] = ApA[(size_t)i * 64];
    aB[i] = ApB[(size_t)i * 64];
  }
  __syncthreads();

  for (int g = 0; g < 5; ++g) {
    const int cur = g & 1, nxt = cur ^ 1;
    if (g + 1 < 5) {
#pragma unroll
      for (int j = 0; j < 7; ++j)
        if (gok[j]) bls[nxt * 1600 + tid + 256 * j] = rb[j];
    }
    if (g + 2 < 5) {
#pragma unroll
      for (int j = 0; j < 7; ++j)
        if (gok[j]) rb[j] = gsrc[j][(g + 2) * 320];
    }
    if (g + 1 < 5) {
#pragma unroll
      for (int i = 0; i < 5; ++i) {
        nA[i] = ApA[(size_t)((g + 1) * 5 + i) * 64];
        nB[i] = ApB[(size_t)((g + 1) * 5 + i) * 64];
      }
    }
#pragma unroll
    for (int i = 0; i < 5; ++i) {
#pragma unroll
      for (int s = 0; s < NSL; ++s) {
        i32x4 b = bls[cur * 1600 + (i * 5 + s) * 64 + lane];
        CA[s] = __builtin_amdgcn_mfma_i32_32x32x32_i8(aA[i], b, CA[s], 0, 0, 0);
        CB[s] = __builtin_amdgcn_mfma_i32_32x32x32_i8(aB[i], b, CB[s], 0, 0, 0);
      }
    }
    __syncthreads();
#pragma unroll
    for (int i = 0; i < 5; ++i) { aA[i] = nA[i]; aB[i] = nB[i]; }
  }

  int o = nt * 32 + (lane & 31);
  int rb2 = 4 * (lane >> 5);
#pragma unroll
  for (int r = 0; r < 16; ++r) {
    int row = (r & 3) + 8 * (r >> 2) + rb2;
    long long TA = (long long)CA[4][r];
    TA = (TA << 8) + (long long)CA[3][r];
    TA = (TA << 8) + (long long)CA[2][r];
    TA = (TA << 8) + (long long)CA[1][r];
    TA = (TA << 8) + (long long)CA[0][r];
    long long TB = (long long)CB[4][r];
    TB = (TB << 8) + (long long)CB[3][r];
    TB = (TB << 8) + (long long)CB[2][r];
    TB = (TB << 8) + (long long)CB[1][r];
    TB = (TB << 8) + (long long)CB[0][r];
    int bA = mtA * 32 + row;
    size_t i0 = ((size_t)tl * 1024 + bA) * 1024 + o;
    size_t i1 = ((size_t)tl * 1024 + bA + 32) * 1024 + o;
    T1L[i0] = (int)TA;
    T1H[i0] = (short)(TA >> 32);
    T1L[i1] = (int)TB;
    T1H[i1] = (short)(TB >> 32);
  }
}

// ---------------------------------------------------------------------------
// rec1: layer-1 membrane recurrence (memory-bound), with next-chunk spikegen
// blocks appended as VALU backfill (blockIdx >= 512).
// T = ((int64)Th << 32) + (uint32)Tl ; I = (double)T * 2^-40 (exact).
// ---------------------------------------------------------------------------
__global__ __launch_bounds__(256) void rec1_kernel(
    const int* __restrict__ T1L, const short* __restrict__ T1H,
    signed char* __restrict__ h1sc,
    double* __restrict__ h1m_st, signed char* __restrict__ h1s_st,
    const float* __restrict__ tau0, int t0, int C,
    const float* __restrict__ x, i32x4* __restrict__ A, int t1) {
  if (blockIdx.x >= 512) {
    spike_block(x, A, t1, blockIdx.x - 512, threadIdx.x);
    return;
  }
  int tid = threadIdx.x;
  int lane = tid & 63, sub = tid >> 6;
  int b = blockIdx.x * 2 + (sub >> 1);
  int obase = (sub & 1) * 512 + lane;           // o = obase + 64*j
  double alpha = 1.0 / (1.0 + exp(-(double)tau0[0]));
  double m[8], s[8];
  if (t0 == 0) {
#pragma unroll
    for (int j = 0; j < 8; ++j) { m[j] = 0.5; s[j] = 0.0; }
  } else {
#pragma unroll
    for (int j = 0; j < 8; ++j) {
      m[j] = h1m_st[(size_t)b * 1024 + obase + 64 * j];
      s[j] = (double)h1s_st[(size_t)b * 1024 + obase + 64 * j];
    }
  }
  for (int tl = 0; tl < C; ++tl) {
    const int*   Lp = T1L + ((size_t)tl * 1024 + b) * 1024 + obase;
    const short* Hp = T1H + ((size_t)tl * 1024 + b) * 1024 + obase;
    signed char* Sp = h1sc + ((size_t)tl * 1024 + b) * 1024 + obase;
#pragma unroll
    for (int j = 0; j < 8; ++j) {
      long long T = ((long long)Hp[64 * j] << 32) +
                    (long long)(unsigned int)Lp[64 * j];
      double I = (double)T * 0x1p-40;
      m[j] = (s[j] != 0.0 ? 0.0 : m[j] * alpha) + I;
      bool sp = (m[j] - 1.0) >= 0.0;
      s[j] = sp ? 1.0 : 0.0;
      Sp[64 * j] = sp ? 1 : 0;
    }
  }
#pragma unroll
  for (int j = 0; j < 8; ++j) {
    h1m_st[(size_t)b * 1024 + obase + 64 * j] = m[j];
    h1s_st[(size_t)b * 1024 + obase + 64 * j] = (signed char)(s[j] != 0.0 ? 1 : 0);
  }
}

// ---------------------------------------------------------------------------
// GEMM2: M=C*1024, N=128, K=1024, 5 slices. A = h1sc bytes row-major
// (row stride 1024 == A-frag k-order). LDS-staged B (wave w stages slice w,
// wave 0 also slice 4), double-buffered. Flattened 1D grid; next-chunk
// spikegen blocks appended (>= ngemm).
// ---------------------------------------------------------------------------
__global__ __launch_bounds__(256, 3) void gemm2_kernel(
    const signed char* __restrict__ Bf, const signed char* __restrict__ h1sc,
    double* __restrict__ T2, int ngemm,
    const float* __restrict__ x, i32x4* __restrict__ A, int t1, int gofs) {
  if ((int)blockIdx.x >= ngemm) {
    spike_block(x, A, t1, gofs + (int)blockIdx.x - ngemm, threadIdx.x);
    return;
  }
  __shared__ i32x4 bls[2][NSL][64];
  int tid = threadIdx.x, lane = tid & 63, wv = tid >> 6;
  int nt = blockIdx.x & 3;             // 0..3
  int mg = blockIdx.x >> 2;
  int tl = mg >> 3;
  int mt = ((mg & 7) << 2) + wv;
  const signed char* Arow =
      h1sc + ((size_t)tl * 1024 + mt * 32 + (lane & 31)) * 1024 + ((lane >> 5) << 4);
  const i32x4* Bp = (const i32x4*)Bf + lane;
  const bool st4 = (wv == 0);
#define B2_IDX(s, kc) ((size_t)(((s) * 4 + nt) * 32 + (kc)) * 64)

  i32x16 C[NSL];
#pragma unroll
  for (int s = 0; s < NSL; ++s)
#pragma unroll
    for (int i = 0; i < 16; ++i) C[s][i] = 0;

  i32x4 sa = Bp[B2_IDX(wv, 0)];
  i32x4 sb; if (st4) sb = Bp[B2_IDX(4, 0)];
  i32x4 a0 = *(const i32x4*)(Arow);
  i32x4 a1 = *(const i32x4*)(Arow + 32);
  i32x4 a2;
  bls[0][wv][lane] = sa;
  if (st4) bls[0][4][lane] = sb;
  sa = Bp[B2_IDX(wv, 1)];
  if (st4) sb = Bp[B2_IDX(4, 1)];
  __syncthreads();

  for (int kc = 0; kc < 32; ++kc) {
    const int cur = kc & 1, nxt = cur ^ 1;
    if (kc + 1 < 32) {
      bls[nxt][wv][lane] = sa;
      if (st4) bls[nxt][4][lane] = sb;
    }
    if (kc + 2 < 32) {
      sa = Bp[B2_IDX(wv, kc + 2)];
      if (st4) sb = Bp[B2_IDX(4, kc + 2)];
      a2 = *(const i32x4*)(Arow + (size_t)(kc + 2) * 32);
    }
    i32x4 b0 = bls[cur][0][lane], b1 = bls[cur][1][lane], b2 = bls[cur][2][lane];
    i32x4 b3 = bls[cur][3][lane], b4 = bls[cur][4][lane];
    C[0] = __builtin_amdgcn_mfma_i32_32x32x32_i8(a0, b0, C[0], 0, 0, 0);
    C[1] = __builtin_amdgcn_mfma_i32_32x32x32_i8(a0, b1, C[1], 0, 0, 0);
    C[2] = __builtin_amdgcn_mfma_i32_32x32x32_i8(a0, b2, C[2], 0, 0, 0);
    C[3] = __builtin_amdgcn_mfma_i32_32x32x32_i8(a0, b3, C[3], 0, 0, 0);
    C[4] = __builtin_amdgcn_mfma_i32_32x32x32_i8(a0, b4, C[4], 0, 0, 0);
    a0 = a1; a1 = a2;
    __syncthreads();
  }

  int o = nt * 32 + (lane & 31);
  int rb = 4 * (lane >> 5);
#pragma unroll
  for (int r = 0; r < 16; ++r) {
    int row = (r & 3) + 8 * (r >> 2) + rb;
    int b = mt * 32 + row;
    long long T = (long long)C[4][r];
    T = (T << 8) + (long long)C[3][r];
    T = (T << 8) + (long long)C[2][r];
    T = (T << 8) + (long long)C[1][r];
    T = (T << 8) + (long long)C[0][r];
    T2[((size_t)tl * 1024 + b) * 128 + o] = (double)T * 0x1p-40;
  }
}

// ---------------------------------------------------------------------------
// rec2: layer-2 membrane recurrence + AvgPool(10) + pPLI accumulator.
// ---------------------------------------------------------------------------
__global__ __launch_bounds__(256) void rec2_kernel(
    const double* __restrict__ T2, double* __restrict__ h2m_st,
    signed char* __restrict__ h2s_st, double* __restrict__ acc_st,
    const float* __restrict__ tauv, const float* __restrict__ acct,
    int t0, int C, float* __restrict__ out) {
  __shared__ signed char sp[256];
  int tid = threadIdx.x;
  int b = blockIdx.x * 2 + (tid >> 7);
  int o = tid & 127;
  double alpha = 1.0 / (1.0 + exp(-(double)tauv[0]));
  double adec  = 1.0 / (1.0 + exp(-(double)acct[0]));
  double m, s, accv = 0.0;
  bool isPool = (o < 10);
  if (t0 == 0) {
    m = 0.5; s = 0.0;
  } else {
    m = h2m_st[(size_t)b * 128 + o];
    s = (double)h2s_st[(size_t)b * 128 + o];
    if (isPool) accv = acc_st[b * 10 + o];
  }
  for (int tl = 0; tl < C; ++tl) {
    double I = T2[((size_t)tl * 1024 + b) * 128 + o];
    m = (s != 0.0 ? 0.0 : m * alpha) + I;
    bool spk = (m - 1.0) >= 0.0;
    s = spk ? 1.0 : 0.0;
    sp[tid] = spk ? 1 : 0;
    __syncthreads();
    if (isPool) {
      int base = tid & 128;
      int isum = 0;
#pragma unroll
      for (int k = 0; k < 10; ++k) isum += sp[base + o * 10 + k];
      accv = accv * adec + (double)isum / 10.0;
      if (t0 + tl == NSTEPS - 1) out[b * 10 + o] = (float)accv;
    }
    __syncthreads();
  }
  h2m_st[(size_t)b * 128 + o] = m;
  h2s_st[(size_t)b * 128 + o] = (signed char)(s != 0.0 ? 1 : 0);
  if (isPool) acc_st[b * 10 + o] = accv;
}

// ---------------------------------------------------------------------------
extern "C" void kernel_launch(void* const* d_in, const int* in_sizes, int n_in,
                              void* d_out, int out_size, void* d_ws, size_t ws_size,
                              hipStream_t stream) {
  const float* x    = (const float*)d_in[0];
  const float* W1   = (const float*)d_in[1];
  const float* W2   = (const float*)d_in[2];
  const float* tau0 = (const float*)d_in[3];
  const float* tauv = (const float*)d_in[4];
  const float* acct = (const float*)d_in[5];
  float* out = (float*)d_out;
  char*  ws  = (char*)d_ws;

  signed char* B1     = (signed char*)(ws + OFF_B1);
  signed char* B2     = (signed char*)(ws + OFF_B2);
  double*      h1m_st = (double*)(ws + OFF_H1MST);
  signed char* h1s_st = (signed char*)(ws + OFF_H1SST);
  double*      h2m_st = (double*)(ws + OFF_H2MST);
  signed char* h2s_st = (signed char*)(ws + OFF_H2SST);
  double*      acc_st = (double*)(ws + OFF_ACCST);
  signed char* Af     = (signed char*)(ws + OFF_AF);
  i32x4*       Afv    = (i32x4*)Af;

  // adaptive chunking, capped at 13 to keep the chunk working set LLC-resident
  long long avail = (long long)ws_size - (long long)FIXED_END;
  int C = (int)(avail / (long long)PERSTEP);
  if (C < 1) C = 1;
  if (C > 13) C = 13;
  size_t off_t1l  = FIXED_END;
  size_t off_t1h  = off_t1l + (size_t)C * 4194304ull;
  size_t off_h1sc = off_t1h + (size_t)C * 2097152ull;
  size_t off_t2   = off_h1sc + (size_t)C * 1048576ull;
  int*         T1L  = (int*)(ws + off_t1l);
  short*       T1H  = (short*)(ws + off_t1h);
  signed char* h1sc = (signed char*)(ws + off_h1sc);
  double*      T2   = (double*)(ws + off_t2);

  int C0 = (C < NSTEPS) ? C : NSTEPS;
  setup_kernel<<<PREP_BLOCKS + C0 * 200, 256, 0, stream>>>(
      W1, W2, B1, B2, x, Afv);

  for (int t0 = 0; t0 < NSTEPS; t0 += C) {
    int Cc = (NSTEPS - t0 < C) ? (NSTEPS - t0) : C;
    int t1 = t0 + Cc;
    int Cn = (t1 < NSTEPS) ? ((NSTEPS - t1 < C) ? (NSTEPS - t1) : C) : 0;
    int spkTot = Cn * 200;             // spike blocks for next chunk
    int spkA = spkTot / 2;             // backfill on rec1
    int spkB = spkTot - spkA;          // backfill on gemm2
    int ngemm2 = 4 * Cc * 8;

    gemm1_kernel<<<32 * Cc * 4, 256, 0, stream>>>(
        B1, Af + (size_t)t0 * 851968ull, T1L, T1H);
    rec1_kernel<<<512 + spkA, 256, 0, stream>>>(
        T1L, T1H, h1sc, h1m_st, h1s_st, tau0, t0, Cc, x, Afv, t1);
    gemm2_kernel<<<ngemm2 + spkB, 256, 0, stream>>>(
        B2, h1sc, T2, ngemm2, x, Afv, t1, spkA);
    rec2_kernel<<<512, 256, 0, stream>>>(
        T2, h2m_st, h2s_st, acc_st, tauv, acct, t0, Cc, out);
  }
}

// Round 13
// 517.122 us; speedup vs baseline: 1.2603x; 1.2603x over previous
//
#include <hip/hip_runtime.h>
#include <hip/hip_bf16.h>
#include <math.h>

// ---------------------------------------------------------------------------
// sMLP4, time-parallel formulation (exact int8-sliced MFMA, 5 slices):
//   w*2^48 = sum_s d_s 256^s; digits 1..5 used (drop low byte, per-weight
//   err <= 2^-41). Slice dots exact int32; T = Horner(5), I = (double)T*2^-40.
// Round 13: r10 gemm1 K-loop, but B staging via async global_load_lds DMA
//   (16B/lane, wave-uniform LDS base -- no staging VGPRs, no load->write
//   chain) and A prefetch depth 1. K-loop VGPR ~40; __launch_bounds__(256,2)
//   caps VGPR at 96 -> 96+160 AGPR = 256 -> 2 blocks/CU. Two co-resident
//   blocks interleave their per-kc barrier drains (the r10 stall).
//   C cap 13 -> 17 (3 chunks, 13 launches).
//   Trajectory bit-identical to rounds 9-12.
// ---------------------------------------------------------------------------

#define NSTEPS 50
#define KC1 25                     // real K chunks for layer 1 (800 >= 784)
#define NSL 5                      // digit slices (digits 1..5 of 2^48 fix-pt)

typedef __attribute__((ext_vector_type(4)))  int i32x4;
typedef __attribute__((ext_vector_type(16))) int i32x16;

// fixed workspace layout (bytes, all 256-aligned)
#define OFF_B1     0ull            // i8 [5s][32nt][26kc][1024] = 4,259,840
#define OFF_B2     5111808ull      // i8 [5*4*32*1024]  =   655,360
#define OFF_H1MST  5898240ull      // f64[1024*1024]    = 8,388,608
#define OFF_H1SST  14286848ull     // i8 [1024*1024]    = 1,048,576
#define OFF_H2MST  15335424ull     // f64[1024*128]     = 1,048,576
#define OFF_H2SST  16384000ull     // i8 [1024*128]     =   131,072
#define OFF_ACCST  16515072ull     // f64[1024*10]      =    81,920
#define OFF_AF     16596992ull     // i8 [50*32*26*64*16] = 42,598,400
#define FIXED_END  59195392ull
// per-chunk (C steps): T1L C*4,194,304 ; T1H C*2,097,152 ;
//                      h1sc C*1,048,576 ; T2 C*1,048,576  = 8,388,608/step
#define PERSTEP    8388608ull

#define PREP_BLOCKS 19200          // (4,259,840 + 655,360) / 256

// async 16-B global -> LDS DMA (gfx950 global_load_lds_dwordx4)
__device__ __forceinline__ void dma16(const void* g, void* l) {
  __builtin_amdgcn_global_load_lds(
      (const __attribute__((address_space(1))) unsigned int*)g,
      (__attribute__((address_space(3))) unsigned int*)l, 16, 0, 0);
}

// ---------------------------------------------------------------------------
// threefry2x32, key (0,42), partitionable mode: bits(i) = x0^x1 on ctr (0,i)
// ---------------------------------------------------------------------------
__device__ __forceinline__ unsigned int rotl32(unsigned int v, int d) {
#if __has_builtin(__builtin_amdgcn_alignbit)
  return __builtin_amdgcn_alignbit(v, v, (unsigned int)(32 - d));
#else
  return (v << d) | (v >> (32 - d));
#endif
}

__device__ __forceinline__ unsigned int tf_bits(unsigned int i) {
  const unsigned int ks0 = 0u;
  const unsigned int ks1 = 42u;
  const unsigned int ks2 = 0x1BD11BDAu ^ 0u ^ 42u;
  unsigned int x0 = 0u + ks0;
  unsigned int x1 = i + ks1;
#define TF_RND(r) { x0 += x1; x1 = rotl32(x1, r); x1 ^= x0; }
  TF_RND(13) TF_RND(15) TF_RND(26) TF_RND(6)
  x0 += ks1; x1 += ks2 + 1u;
  TF_RND(17) TF_RND(29) TF_RND(16) TF_RND(24)
  x0 += ks2; x1 += ks0 + 2u;
  TF_RND(13) TF_RND(15) TF_RND(26) TF_RND(6)
  x0 += ks0; x1 += ks1 + 3u;
  TF_RND(17) TF_RND(29) TF_RND(16) TF_RND(24)
  x0 += ks1; x1 += ks2 + 4u;
  TF_RND(13) TF_RND(15) TF_RND(26) TF_RND(6)
  x0 += ks2; x1 += ks0 + 5u;
#undef TF_RND
  return x0 ^ x1;
}

// ---------------------------------------------------------------------------
// spikegen role (one block = 4 waves = 4 (t,mt,kc) groups), steps [t0, ...).
// A-frag: lane holds A[m = mt*32+(lane&31)][k = kc*32+(lane>>5)*16+jj].
// Integer compare: u < x  <=>  (bits>>9) < ceil(x*2^23)   (both exact).
// ---------------------------------------------------------------------------
__device__ __forceinline__ void spike_block(
    const float* __restrict__ x, i32x4* __restrict__ A, int t0, int gblk,
    int tid) {
  int g = gblk * 4 + (tid >> 6);
  int lane = tid & 63;
  int kc = g % 25;
  int r = g / 25;                     // chunk-local tl*32 + mt
  int mt = r & 31;
  int t = t0 + (r >> 5);
  int b = mt * 32 + (lane & 31);
  int j0 = kc * 32 + ((lane >> 5) << 4);
  unsigned int wds[4] = {0u, 0u, 0u, 0u};
  if (j0 < 784) {                     // 784 = 49*16: wave-uniform guard
    unsigned int base = (unsigned int)(t * 1024 + b) * 784u + (unsigned int)j0;
    const float* xp = x + b * 784 + j0;
#pragma unroll
    for (int q = 0; q < 4; ++q) {
      float4 xv = *(const float4*)(xp + 4 * q);
      unsigned int K0 = (unsigned int)(int)ceilf(xv.x * 8388608.0f);
      unsigned int K1 = (unsigned int)(int)ceilf(xv.y * 8388608.0f);
      unsigned int K2 = (unsigned int)(int)ceilf(xv.z * 8388608.0f);
      unsigned int K3 = (unsigned int)(int)ceilf(xv.w * 8388608.0f);
      unsigned int w4 = 0u;
      if ((tf_bits(base + 4 * q + 0) >> 9) < K0) w4 |= 1u;
      if ((tf_bits(base + 4 * q + 1) >> 9) < K1) w4 |= 1u << 8;
      if ((tf_bits(base + 4 * q + 2) >> 9) < K2) w4 |= 1u << 16;
      if ((tf_bits(base + 4 * q + 3) >> 9) < K3) w4 |= 1u << 24;
      wds[q] = w4;
    }
  }
  i32x4 v;
  v.x = (int)wds[0]; v.y = (int)wds[1]; v.z = (int)wds[2]; v.w = (int)wds[3];
  A[(size_t)(((t * 32 + mt) * 26) + kc) * 64 + lane] = v;
}

// ---------------------------------------------------------------------------
// setup: prep (weight slicing) blocks first, chunk-0 spikegen blocks backfill.
// B1 layout (s-major): B1[(((s*32+nt)*26)+kc)*1024 + lane*16 + jj],
// digit s+1 of w*2^48. B2 layout: [(s*4+nt)*32+kc][64][16].
// B-frag (32x32x32 i8): lane holds B[k = kc*32+(lane>>5)*16+jj][n],
// n = nt*32+(lane&31). (HW-validated layout)
// ---------------------------------------------------------------------------
__global__ __launch_bounds__(256) void setup_kernel(
    const float* __restrict__ W1, const float* __restrict__ W2,
    signed char* __restrict__ B1, signed char* __restrict__ B2,
    const float* __restrict__ x, i32x4* __restrict__ A) {
  if (blockIdx.x >= PREP_BLOCKS) {
    spike_block(x, A, 0, blockIdx.x - PREP_BLOCKS, threadIdx.x);
    return;
  }
  int idx = blockIdx.x * 256 + threadIdx.x;
  const int NB1 = NSL * 32 * 26 * 1024;
  const int NB2 = NSL * 4 * 32 * 1024;
  float w;
  int s;
  signed char* dst;
  if (idx < NB1) {
    int jj = idx & 15;
    int lane = (idx >> 4) & 63;
    int kc = (idx >> 10) % 26;
    int rest = (idx >> 10) / 26;
    int nt = rest & 31;
    s = rest >> 5;                    // 0..4
    int k = kc * 32 + ((lane >> 5) << 4) + jj;
    int o = nt * 32 + (lane & 31);
    w = (o < 1000 && k < 784) ? W1[o * 784 + k] : 0.0f;
    dst = B1 + idx;
  } else {
    int m = idx - NB1;
    if (m >= NB2) return;
    int jj = m & 15;
    int lane = (m >> 4) & 63;
    int kc = (m >> 10) & 31;
    int rest = (m >> 10) >> 5;
    int nt = rest & 3;
    s = rest >> 2;                    // 0..4
    int k = kc * 32 + ((lane >> 5) << 4) + jj;
    int o = nt * 32 + (lane & 31);
    w = (o < 100 && k < 1000) ? W2[o * 1000 + k] : 0.0f;
    dst = B2 + m;
  }
  long long V = llrint((double)w * 281474976710656.0);  // w * 2^48, exact
  signed char d = 0;
  for (int q = 0; q <= s + 1; ++q) {  // extract digit s+1
    d = (signed char)(V & 0xFF);
    V = (V - (long long)d) >> 8;
  }
  *dst = d;
}

// ---------------------------------------------------------------------------
// GEMM1: M=C*1024 (t-batched), N=1024, K=800 (25 chunks), 5 slices.
// r10 shape: block = 4 waves sharing one nt, each wave TWO 32x32 m-tiles x
// 5 slices (160 AGPR). B staged via async global_load_lds DMA (wave w ->
// slice w; wave 0 also slice 4), double-buffered 10 KB LDS; A prefetch
// depth 1. launch_bounds(256,2): VGPR capped at 96 -> 256 regs/wave ->
// 2 blocks/CU; the co-resident block computes through this block's
// per-kc barrier vmcnt drain. XCD swizzle: nt = (id&7)*4 + ((id>>3)&3).
// T1 out = int32 lo + int16 hi planes (exact split fixed point).
// ---------------------------------------------------------------------------
__global__ __launch_bounds__(256, 2) void gemm1_kernel(
    const signed char* __restrict__ Bf, const signed char* __restrict__ Afc,
    int* __restrict__ T1L, short* __restrict__ T1H) {
  __shared__ i32x4 bls[2][NSL][64];    // 10 KB
  int tid = threadIdx.x, lane = tid & 63, wv = tid >> 6;
  int id = blockIdx.x;
  int low5 = id & 31;
  int nt = ((low5 & 7) << 2) | ((low5 >> 3) & 3);   // XCD-pinned nt
  int mg = id >> 5;
  int tl = mg >> 2;
  int q  = mg & 3;
  int mtA = q * 8 + wv * 2;            // and mtA+1
  const i32x4* ApA = (const i32x4*)Afc + (size_t)((tl * 32 + mtA) * 26) * 64 + lane;
  const i32x4* ApB = ApA + 26 * 64;
  const i32x4* Bp = (const i32x4*)Bf + lane;
#define B1_IDX(s, kc) ((size_t)(((s) * 32 + nt) * 26 + (kc)) * 64)
  const bool st4 = (wv == 0);

  i32x16 CA[NSL], CB[NSL];
#pragma unroll
  for (int s = 0; s < NSL; ++s)
#pragma unroll
    for (int i = 0; i < 16; ++i) { CA[s][i] = 0; CB[s][i] = 0; }

  // prologue: DMA kc=0 into buf0, load A(kc=0)
  dma16(&Bp[B1_IDX(wv, 0)], &bls[0][wv][0]);
  if (st4) dma16(&Bp[B1_IDX(4, 0)], &bls[0][4][0]);
  i32x4 aA0 = ApA[0], aB0 = ApB[0];
  i32x4 aA1, aB1;
  __syncthreads();

  for (int kc = 0; kc < KC1; ++kc) {
    const int cur = kc & 1, nxt = cur ^ 1;
    if (kc + 1 < KC1) {
      dma16(&Bp[B1_IDX(wv, kc + 1)], &bls[nxt][wv][0]);
      if (st4) dma16(&Bp[B1_IDX(4, kc + 1)], &bls[nxt][4][0]);
      aA1 = ApA[(size_t)(kc + 1) * 64];
      aB1 = ApB[(size_t)(kc + 1) * 64];
    }
#pragma unroll
    for (int s = 0; s < NSL; ++s) {
      i32x4 b = bls[cur][s][lane];
      CA[s] = __builtin_amdgcn_mfma_i32_32x32x32_i8(aA0, b, CA[s], 0, 0, 0);
      CB[s] = __builtin_amdgcn_mfma_i32_32x32x32_i8(aB0, b, CB[s], 0, 0, 0);
    }
    __syncthreads();
    aA0 = aA1; aB0 = aB1;
  }

  int o = nt * 32 + (lane & 31);
  int rb = 4 * (lane >> 5);
#pragma unroll
  for (int r = 0; r < 16; ++r) {
    int row = (r & 3) + 8 * (r >> 2) + rb;
    long long TA = (long long)CA[4][r];
    TA = (TA << 8) + (long long)CA[3][r];
    TA = (TA << 8) + (long long)CA[2][r];
    TA = (TA << 8) + (long long)CA[1][r];
    TA = (TA << 8) + (long long)CA[0][r];
    long long TB = (long long)CB[4][r];
    TB = (TB << 8) + (long long)CB[3][r];
    TB = (TB << 8) + (long long)CB[2][r];
    TB = (TB << 8) + (long long)CB[1][r];
    TB = (TB << 8) + (long long)CB[0][r];
    int bA = mtA * 32 + row;
    size_t i0 = ((size_t)tl * 1024 + bA) * 1024 + o;
    size_t i1 = ((size_t)tl * 1024 + bA + 32) * 1024 + o;
    T1L[i0] = (int)TA;
    T1H[i0] = (short)(TA >> 32);
    T1L[i1] = (int)TB;
    T1H[i1] = (short)(TB >> 32);
  }
}

// ---------------------------------------------------------------------------
// rec1: layer-1 membrane recurrence (memory-bound), with next-chunk spikegen
// blocks appended as VALU backfill (blockIdx >= 512).
// T = ((int64)Th << 32) + (uint32)Tl ; I = (double)T * 2^-40 (exact).
// ---------------------------------------------------------------------------
__global__ __launch_bounds__(256) void rec1_kernel(
    const int* __restrict__ T1L, const short* __restrict__ T1H,
    signed char* __restrict__ h1sc,
    double* __restrict__ h1m_st, signed char* __restrict__ h1s_st,
    const float* __restrict__ tau0, int t0, int C,
    const float* __restrict__ x, i32x4* __restrict__ A, int t1) {
  if (blockIdx.x >= 512) {
    spike_block(x, A, t1, blockIdx.x - 512, threadIdx.x);
    return;
  }
  int tid = threadIdx.x;
  int lane = tid & 63, sub = tid >> 6;
  int b = blockIdx.x * 2 + (sub >> 1);
  int obase = (sub & 1) * 512 + lane;           // o = obase + 64*j
  double alpha = 1.0 / (1.0 + exp(-(double)tau0[0]));
  double m[8], s[8];
  if (t0 == 0) {
#pragma unroll
    for (int j = 0; j < 8; ++j) { m[j] = 0.5; s[j] = 0.0; }
  } else {
#pragma unroll
    for (int j = 0; j < 8; ++j) {
      m[j] = h1m_st[(size_t)b * 1024 + obase + 64 * j];
      s[j] = (double)h1s_st[(size_t)b * 1024 + obase + 64 * j];
    }
  }
  for (int tl = 0; tl < C; ++tl) {
    const int*   Lp = T1L + ((size_t)tl * 1024 + b) * 1024 + obase;
    const short* Hp = T1H + ((size_t)tl * 1024 + b) * 1024 + obase;
    signed char* Sp = h1sc + ((size_t)tl * 1024 + b) * 1024 + obase;
#pragma unroll
    for (int j = 0; j < 8; ++j) {
      long long T = ((long long)Hp[64 * j] << 32) +
                    (long long)(unsigned int)Lp[64 * j];
      double I = (double)T * 0x1p-40;
      m[j] = (s[j] != 0.0 ? 0.0 : m[j] * alpha) + I;
      bool sp = (m[j] - 1.0) >= 0.0;
      s[j] = sp ? 1.0 : 0.0;
      Sp[64 * j] = sp ? 1 : 0;
    }
  }
#pragma unroll
  for (int j = 0; j < 8; ++j) {
    h1m_st[(size_t)b * 1024 + obase + 64 * j] = m[j];
    h1s_st[(size_t)b * 1024 + obase + 64 * j] = (signed char)(s[j] != 0.0 ? 1 : 0);
  }
}

// ---------------------------------------------------------------------------
// GEMM2: M=C*1024, N=128, K=1024, 5 slices. A = h1sc bytes row-major
// (row stride 1024 == A-frag k-order). LDS-staged B (wave w stages slice w,
// wave 0 also slice 4), double-buffered. Flattened 1D grid; next-chunk
// spikegen blocks appended (>= ngemm).
// ---------------------------------------------------------------------------
__global__ __launch_bounds__(256, 3) void gemm2_kernel(
    const signed char* __restrict__ Bf, const signed char* __restrict__ h1sc,
    double* __restrict__ T2, int ngemm,
    const float* __restrict__ x, i32x4* __restrict__ A, int t1, int gofs) {
  if ((int)blockIdx.x >= ngemm) {
    spike_block(x, A, t1, gofs + (int)blockIdx.x - ngemm, threadIdx.x);
    return;
  }
  __shared__ i32x4 bls[2][NSL][64];
  int tid = threadIdx.x, lane = tid & 63, wv = tid >> 6;
  int nt = blockIdx.x & 3;             // 0..3
  int mg = blockIdx.x >> 2;
  int tl = mg >> 3;
  int mt = ((mg & 7) << 2) + wv;
  const signed char* Arow =
      h1sc + ((size_t)tl * 1024 + mt * 32 + (lane & 31)) * 1024 + ((lane >> 5) << 4);
  const i32x4* Bp = (const i32x4*)Bf + lane;
  const bool st4 = (wv == 0);
#define B2_IDX(s, kc) ((size_t)(((s) * 4 + nt) * 32 + (kc)) * 64)

  i32x16 C[NSL];
#pragma unroll
  for (int s = 0; s < NSL; ++s)
#pragma unroll
    for (int i = 0; i < 16; ++i) C[s][i] = 0;

  i32x4 sa = Bp[B2_IDX(wv, 0)];
  i32x4 sb; if (st4) sb = Bp[B2_IDX(4, 0)];
  i32x4 a0 = *(const i32x4*)(Arow);
  i32x4 a1 = *(const i32x4*)(Arow + 32);
  i32x4 a2;
  bls[0][wv][lane] = sa;
  if (st4) bls[0][4][lane] = sb;
  sa = Bp[B2_IDX(wv, 1)];
  if (st4) sb = Bp[B2_IDX(4, 1)];
  __syncthreads();

  for (int kc = 0; kc < 32; ++kc) {
    const int cur = kc & 1, nxt = cur ^ 1;
    if (kc + 1 < 32) {
      bls[nxt][wv][lane] = sa;
      if (st4) bls[nxt][4][lane] = sb;
    }
    if (kc + 2 < 32) {
      sa = Bp[B2_IDX(wv, kc + 2)];
      if (st4) sb = Bp[B2_IDX(4, kc + 2)];
      a2 = *(const i32x4*)(Arow + (size_t)(kc + 2) * 32);
    }
    i32x4 b0 = bls[cur][0][lane], b1 = bls[cur][1][lane], b2 = bls[cur][2][lane];
    i32x4 b3 = bls[cur][3][lane], b4 = bls[cur][4][lane];
    C[0] = __builtin_amdgcn_mfma_i32_32x32x32_i8(a0, b0, C[0], 0, 0, 0);
    C[1] = __builtin_amdgcn_mfma_i32_32x32x32_i8(a0, b1, C[1], 0, 0, 0);
    C[2] = __builtin_amdgcn_mfma_i32_32x32x32_i8(a0, b2, C[2], 0, 0, 0);
    C[3] = __builtin_amdgcn_mfma_i32_32x32x32_i8(a0, b3, C[3], 0, 0, 0);
    C[4] = __builtin_amdgcn_mfma_i32_32x32x32_i8(a0, b4, C[4], 0, 0, 0);
    a0 = a1; a1 = a2;
    __syncthreads();
  }

  int o = nt * 32 + (lane & 31);
  int rb = 4 * (lane >> 5);
#pragma unroll
  for (int r = 0; r < 16; ++r) {
    int row = (r & 3) + 8 * (r >> 2) + rb;
    int b = mt * 32 + row;
    long long T = (long long)C[4][r];
    T = (T << 8) + (long long)C[3][r];
    T = (T << 8) + (long long)C[2][r];
    T = (T << 8) + (long long)C[1][r];
    T = (T << 8) + (long long)C[0][r];
    T2[((size_t)tl * 1024 + b) * 128 + o] = (double)T * 0x1p-40;
  }
}

// ---------------------------------------------------------------------------
// rec2: layer-2 membrane recurrence + AvgPool(10) + pPLI accumulator.
// ---------------------------------------------------------------------------
__global__ __launch_bounds__(256) void rec2_kernel(
    const double* __restrict__ T2, double* __restrict__ h2m_st,
    signed char* __restrict__ h2s_st, double* __restrict__ acc_st,
    const float* __restrict__ tauv, const float* __restrict__ acct,
    int t0, int C, float* __restrict__ out) {
  __shared__ signed char sp[256];
  int tid = threadIdx.x;
  int b = blockIdx.x * 2 + (tid >> 7);
  int o = tid & 127;
  double alpha = 1.0 / (1.0 + exp(-(double)tauv[0]));
  double adec  = 1.0 / (1.0 + exp(-(double)acct[0]));
  double m, s, accv = 0.0;
  bool isPool = (o < 10);
  if (t0 == 0) {
    m = 0.5; s = 0.0;
  } else {
    m = h2m_st[(size_t)b * 128 + o];
    s = (double)h2s_st[(size_t)b * 128 + o];
    if (isPool) accv = acc_st[b * 10 + o];
  }
  for (int tl = 0; tl < C; ++tl) {
    double I = T2[((size_t)tl * 1024 + b) * 128 + o];
    m = (s != 0.0 ? 0.0 : m * alpha) + I;
    bool spk = (m - 1.0) >= 0.0;
    s = spk ? 1.0 : 0.0;
    sp[tid] = spk ? 1 : 0;
    __syncthreads();
    if (isPool) {
      int base = tid & 128;
      int isum = 0;
#pragma unroll
      for (int k = 0; k < 10; ++k) isum += sp[base + o * 10 + k];
      accv = accv * adec + (double)isum / 10.0;
      if (t0 + tl == NSTEPS - 1) out[b * 10 + o] = (float)accv;
    }
    __syncthreads();
  }
  h2m_st[(size_t)b * 128 + o] = m;
  h2s_st[(size_t)b * 128 + o] = (signed char)(s != 0.0 ? 1 : 0);
  if (isPool) acc_st[b * 10 + o] = accv;
}

// ---------------------------------------------------------------------------
extern "C" void kernel_launch(void* const* d_in, const int* in_sizes, int n_in,
                              void* d_out, int out_size, void* d_ws, size_t ws_size,
                              hipStream_t stream) {
  const float* x    = (const float*)d_in[0];
  const float* W1   = (const float*)d_in[1];
  const float* W2   = (const float*)d_in[2];
  const float* tau0 = (const float*)d_in[3];
  const float* tauv = (const float*)d_in[4];
  const float* acct = (const float*)d_in[5];
  float* out = (float*)d_out;
  char*  ws  = (char*)d_ws;

  signed char* B1     = (signed char*)(ws + OFF_B1);
  signed char* B2     = (signed char*)(ws + OFF_B2);
  double*      h1m_st = (double*)(ws + OFF_H1MST);
  signed char* h1s_st = (signed char*)(ws + OFF_H1SST);
  double*      h2m_st = (double*)(ws + OFF_H2MST);
  signed char* h2s_st = (signed char*)(ws + OFF_H2SST);
  double*      acc_st = (double*)(ws + OFF_ACCST);
  signed char* Af     = (signed char*)(ws + OFF_AF);
  i32x4*       Afv    = (i32x4*)Af;

  // adaptive chunking, capped at 17 (3 chunks; chunk buffers ~143 MB)
  long long avail = (long long)ws_size - (long long)FIXED_END;
  int C = (int)(avail / (long long)PERSTEP);
  if (C < 1) C = 1;
  if (C > 17) C = 17;
  size_t off_t1l  = FIXED_END;
  size_t off_t1h  = off_t1l + (size_t)C * 4194304ull;
  size_t off_h1sc = off_t1h + (size_t)C * 2097152ull;
  size_t off_t2   = off_h1sc + (size_t)C * 1048576ull;
  int*         T1L  = (int*)(ws + off_t1l);
  short*       T1H  = (short*)(ws + off_t1h);
  signed char* h1sc = (signed char*)(ws + off_h1sc);
  double*      T2   = (double*)(ws + off_t2);

  int C0 = (C < NSTEPS) ? C : NSTEPS;
  setup_kernel<<<PREP_BLOCKS + C0 * 200, 256, 0, stream>>>(
      W1, W2, B1, B2, x, Afv);

  for (int t0 = 0; t0 < NSTEPS; t0 += C) {
    int Cc = (NSTEPS - t0 < C) ? (NSTEPS - t0) : C;
    int t1 = t0 + Cc;
    int Cn = (t1 < NSTEPS) ? ((NSTEPS - t1 < C) ? (NSTEPS - t1) : C) : 0;
    int spkTot = Cn * 200;             // spike blocks for next chunk
    int spkA = spkTot / 2;             // backfill on rec1
    int spkB = spkTot - spkA;          // backfill on gemm2
    int ngemm2 = 4 * Cc * 8;

    gemm1_kernel<<<32 * Cc * 4, 256, 0, stream>>>(
        B1, Af + (size_t)t0 * 851968ull, T1L, T1H);
    rec1_kernel<<<512 + spkA, 256, 0, stream>>>(
        T1L, T1H, h1sc, h1m_st, h1s_st, tau0, t0, Cc, x, Afv, t1);
    gemm2_kernel<<<ngemm2 + spkB, 256, 0, stream>>>(
        B2, h1sc, T2, ngemm2, x, Afv, t1, spkA);
    rec2_kernel<<<512, 256, 0, stream>>>(
        T2, h2m_st, h2s_st, acc_st, tauv, acct, t0, Cc, out);
  }
}